// Round 11
// baseline (209.542 us; speedup 1.0000x reference)
//
#include <hip/hip_runtime.h>

// MHA: B=2, S=2048, D=1024, H=16, hd=64. fp32 in/out, bf16 MFMA internally.
// R20: final attn chain experiment. Split dependent-MFMA chains:
// QK: s_a=k0q0+k1q1, s_b=k2q2+k3q3 (2-deep instead of 4-deep; merged by
// 16 v_add into exp). PV: 4 independent accumulators o0a/o0b/o1a/o1b
// (1-deep; summed once in epilogue). +48 VGPR, no spill.
// Pre-commit: if attn delta < 1us, floor is issue-bound -> ROOFLINE.
// Rest identical to R19 (best: 208.7us; attn 66.4).

typedef __bf16 bf16;
typedef __bf16 bf16x2 __attribute__((ext_vector_type(2)));
typedef __bf16 bf16x4 __attribute__((ext_vector_type(4)));
typedef __bf16 bf16x8 __attribute__((ext_vector_type(8)));
typedef float f32x4 __attribute__((ext_vector_type(4)));
typedef float f32x16 __attribute__((ext_vector_type(16)));

#define MFMA(a, b, c) __builtin_amdgcn_mfma_f32_16x16x32_bf16((a), (b), (c), 0, 0, 0)
#define MFMA32(a, b, c) __builtin_amdgcn_mfma_f32_32x32x16_bf16((a), (b), (c), 0, 0, 0)

#if __has_builtin(__builtin_amdgcn_exp2f)
#define EXP2(x) __builtin_amdgcn_exp2f(x)
#else
#define EXP2(x) exp2f(x)
#endif

__device__ __forceinline__ void load_lds16(const bf16* g, void* l) {
    __builtin_amdgcn_global_load_lds(
        (const __attribute__((address_space(1))) unsigned int*)g,
        (__attribute__((address_space(3))) unsigned int*)l, 16, 0, 0);
}

// ---------------- prep: cast x, transpose w_qkv/w_out ----------------
__global__ __launch_bounds__(256) void prep_kernel(
    const float* __restrict__ x, bf16* __restrict__ xb,
    const float* __restrict__ w_qkv, bf16* __restrict__ wqkvT,
    const float* __restrict__ w_out, bf16* __restrict__ woutT) {
    __shared__ float tile[32][33];
    int blk = blockIdx.x;
    int t = threadIdx.x;
    if (blk < 4096) {
        int i = blk * 256 + t;
        float4 v = ((const float4*)x)[i];
        bf16x4 o = {(bf16)v.x, (bf16)v.y, (bf16)v.z, (bf16)v.w};
        ((bf16x4*)xb)[i] = o;
    } else if (blk < 4096 + 3072) {
        int flat = blk - 4096;
        int bx = (flat % 96) * 32, by = (flat / 96) * 32;
        int tx = t & 31, ty = t >> 5;
        for (int i = 0; i < 32; i += 8)
            tile[ty + i][tx] = w_qkv[(size_t)(by + ty + i) * 3072 + bx + tx];
        __syncthreads();
        for (int i = 0; i < 32; i += 8)
            wqkvT[(size_t)(bx + ty + i) * 1024 + by + tx] = (bf16)tile[tx][ty + i];
    } else {
        int flat = blk - (4096 + 3072);
        int bx = (flat % 32) * 32, by = (flat / 32) * 32;
        int tx = t & 31, ty = t >> 5;
        for (int i = 0; i < 32; i += 8)
            tile[ty + i][tx] = w_out[(size_t)(by + ty + i) * 1024 + bx + tx];
        __syncthreads();
        for (int i = 0; i < 32; i += 8)
            woutT[(size_t)(bx + ty + i) * 1024 + by + tx] = (bf16)tile[tx][ty + i];
    }
}

// ---------------- GEMM1 + mask prep (fused launch) ----------------
__global__ __launch_bounds__(256) void gemm_qkv_kernel(
    const bf16* __restrict__ A, const bf16* __restrict__ BT,
    const float* __restrict__ bias,
    bf16* __restrict__ Q, bf16* __restrict__ K, bf16* __restrict__ VT,
    const float* __restrict__ mask, bf16* __restrict__ maskb) {
    __shared__ __attribute__((aligned(16))) char lds[2][16384];  // A[0,8K) B[8K,16K)
    int blk0 = blockIdx.x;
    int t = threadIdx.x;
    if (blk0 >= 768) {
        // ---- mask prep branch (no barriers; uniform per block) ----
        int flat = blk0 - 768;
        int idx4 = flat * 256 + t;          // 0 .. 2048*2048/4-1
        float4 v = ((const float4*)mask)[idx4];
        int row = idx4 >> 9;                // 512 float4 per row
        int k = (idx4 & 511) * 4;
        int g = (k & 31) >> 2;
        int pos = (k & ~31) + ((g & 1) << 4) + ((g >> 1) << 2);
        const float L2E = 1.44269504089f;
        bf16x4 o = {(bf16)(v.x * L2E), (bf16)(v.y * L2E),
                    (bf16)(v.z * L2E), (bf16)(v.w * L2E)};
        *(bf16x4*)(&maskb[(size_t)row * 2048 + pos]) = o;
        return;
    }
    int bm = blk0 & 31, bn = blk0 >> 5;
    int w = t >> 6, lane = t & 63, g = lane >> 4, l16 = lane & 15;
    int wm = (w >> 1) * 64, wn = (w & 1) * 64;
    f32x4 acc[4][4] = {};
    const bf16* Ablk = A + (size_t)(bm * 128) * 1024;
    const bf16* Bblk = BT + (size_t)(bn * 128) * 1024;
    int srow = t >> 2;
    int scg = (t & 3) ^ (srow & 3);
    const bf16* ag0 = Ablk + (size_t)srow * 1024 + scg * 8;
    const bf16* ag1 = ag0 + 64 * 1024;
    const bf16* bg0 = Bblk + (size_t)srow * 1024 + scg * 8;
    const bf16* bg1 = bg0 + 64 * 1024;

    load_lds16(ag0, lds[0] + t * 16);
    load_lds16(ag1, lds[0] + 4096 + t * 16);
    load_lds16(bg0, lds[0] + 8192 + t * 16);
    load_lds16(bg1, lds[0] + 12288 + t * 16);
    asm volatile("s_waitcnt vmcnt(0)" ::: "memory");

    int sw = l16 & 3;
#pragma unroll 2
    for (int j = 0; j < 32; j++) {
        asm volatile("s_barrier" ::: "memory");
        int jp = j + 1 < 32 ? j + 1 : 31;
        char* dst = lds[(j + 1) & 1];
        load_lds16(ag0 + jp * 32, dst + t * 16);
        load_lds16(ag1 + jp * 32, dst + 4096 + t * 16);
        load_lds16(bg0 + jp * 32, dst + 8192 + t * 16);
        load_lds16(bg1 + jp * 32, dst + 12288 + t * 16);

        const bf16* As = (const bf16*)lds[j & 1];
        const bf16* Bs = (const bf16*)(lds[j & 1] + 8192);
        bf16x8 af[4], bfr[4];
#pragma unroll
        for (int mi = 0; mi < 4; mi++) {
            int row = wm + mi * 16 + l16;
            af[mi] = *(const bf16x8*)(&As[row * 32 + (g ^ sw) * 8]);
        }
#pragma unroll
        for (int ni = 0; ni < 4; ni++) {
            int row = wn + ni * 16 + l16;
            bfr[ni] = *(const bf16x8*)(&Bs[row * 32 + (g ^ sw) * 8]);
        }
#pragma unroll
        for (int mi = 0; mi < 4; mi++)
#pragma unroll
            for (int ni = 0; ni < 4; ni++)
                acc[mi][ni] = MFMA(bfr[ni], af[mi], acc[mi][ni]);  // D^T
        asm volatile("s_waitcnt vmcnt(0)" ::: "memory");
    }
    __syncthreads();  // publish all DMA before LDS reuse as vtile

    bf16* vt = (bf16*)lds;  // V-half transpose tile [64 d][136 s]
    int b = bm >> 4;
    int row0 = (bm & 15) * 128 + wm;
    int half_col = bn * 128 + wn;
    int h = half_col / 192, tt = half_col % 192;  // wave-uniform
    size_t bh = (size_t)(b * 16 + h);

    if (tt < 128) {
        bf16* base = (tt == 0 ? Q : K) + bh * 2048 * 64;
#pragma unroll
        for (int mi = 0; mi < 4; mi++) {
#pragma unroll
            for (int ni = 0; ni < 4; ni++) {
                int d0 = ni * 16 + g * 4;
                float4 bv = *(const float4*)(&bias[half_col + d0]);
                int s = row0 + mi * 16 + l16;
                bf16x4 pk = {(bf16)(acc[mi][ni][0] + bv.x), (bf16)(acc[mi][ni][1] + bv.y),
                             (bf16)(acc[mi][ni][2] + bv.z), (bf16)(acc[mi][ni][3] + bv.w)};
                *(bf16x4*)(&base[(size_t)s * 64 + d0]) = pk;
            }
        }
    } else {
#pragma unroll
        for (int mi = 0; mi < 4; mi++) {
            int s_local = wm + mi * 16 + l16;
#pragma unroll
            for (int ni = 0; ni < 4; ni++) {
                int d0 = ni * 16 + g * 4;
                float4 bv = *(const float4*)(&bias[half_col + d0]);
                vt[(d0 + 0) * 136 + s_local] = (bf16)(acc[mi][ni][0] + bv.x);
                vt[(d0 + 1) * 136 + s_local] = (bf16)(acc[mi][ni][1] + bv.y);
                vt[(d0 + 2) * 136 + s_local] = (bf16)(acc[mi][ni][2] + bv.z);
                vt[(d0 + 3) * 136 + s_local] = (bf16)(acc[mi][ni][3] + bv.w);
            }
        }
    }
    __syncthreads();

    int hc0 = bn * 128, hc1 = bn * 128 + 64;
    int vhalf = (hc0 % 192 == 128) ? 0 : ((hc1 % 192 == 128) ? 1 : -1);
    if (vhalf >= 0) {
        int vcol = bn * 128 + vhalf * 64;
        size_t vbh = (size_t)(b * 16 + vcol / 192);
        int d = t >> 2, ch = t & 3;
        const bf16* src = &vt[d * 136 + ch * 32];
        bf16* dstp = &VT[(vbh * 64 + d) * 2048 + (bm & 15) * 128 + ch * 32];
#pragma unroll
        for (int k = 0; k < 4; k++)
            *(bf16x8*)(&dstp[k * 8]) = *(const bf16x8*)(&src[k * 8]);
    }
}

// ---------------- GEMM3: vals[4096,1024] @ Wout -> out fp32 ----------------
__global__ __launch_bounds__(256) void gemm_out_kernel(
    const bf16* __restrict__ A, const bf16* __restrict__ BT,
    const float* __restrict__ bias, float* __restrict__ out) {
    __shared__ __attribute__((aligned(16))) char lds[2][12288];  // A[0,8K) B[8K,12K)
    int bm = blockIdx.x, bn = blockIdx.y;
    int t = threadIdx.x;
    int w = t >> 6, lane = t & 63, g = lane >> 4, l16 = lane & 15;
    int wm = (w >> 1) * 64, wn = (w & 1) * 32;
    f32x4 acc[4][2] = {};
    const bf16* Ablk = A + (size_t)(bm * 128) * 1024;
    const bf16* Bblk = BT + (size_t)(bn * 64) * 1024;
    int srow = t >> 2;
    int scg = (t & 3) ^ (srow & 3);
    const bf16* ag0 = Ablk + (size_t)srow * 1024 + scg * 8;
    const bf16* ag1 = ag0 + 64 * 1024;
    const bf16* bg0 = Bblk + (size_t)srow * 1024 + scg * 8;

    load_lds16(ag0, lds[0] + t * 16);
    load_lds16(ag1, lds[0] + 4096 + t * 16);
    load_lds16(bg0, lds[0] + 8192 + t * 16);
    asm volatile("s_waitcnt vmcnt(0)" ::: "memory");

    int sw = l16 & 3;
#pragma unroll 2
    for (int j = 0; j < 32; j++) {
        asm volatile("s_barrier" ::: "memory");
        int jp = j + 1 < 32 ? j + 1 : 31;
        char* dst = lds[(j + 1) & 1];
        load_lds16(ag0 + jp * 32, dst + t * 16);
        load_lds16(ag1 + jp * 32, dst + 4096 + t * 16);
        load_lds16(bg0 + jp * 32, dst + 8192 + t * 16);

        const bf16* As = (const bf16*)lds[j & 1];
        const bf16* Bs = (const bf16*)(lds[j & 1] + 8192);
        bf16x8 af[4], bfr[2];
#pragma unroll
        for (int mi = 0; mi < 4; mi++) {
            int row = wm + mi * 16 + l16;
            af[mi] = *(const bf16x8*)(&As[row * 32 + (g ^ sw) * 8]);
        }
#pragma unroll
        for (int ni = 0; ni < 2; ni++) {
            int row = wn + ni * 16 + l16;
            bfr[ni] = *(const bf16x8*)(&Bs[row * 32 + (g ^ sw) * 8]);
        }
#pragma unroll
        for (int mi = 0; mi < 4; mi++)
#pragma unroll
            for (int ni = 0; ni < 2; ni++)
                acc[mi][ni] = MFMA(bfr[ni], af[mi], acc[mi][ni]);  // D^T
        asm volatile("s_waitcnt vmcnt(0)" ::: "memory");
    }

#pragma unroll
    for (int mi = 0; mi < 4; mi++) {
#pragma unroll
        for (int ni = 0; ni < 2; ni++) {
            int row = bm * 128 + wm + mi * 16 + l16;
            int col0 = bn * 64 + wn + ni * 16 + g * 4;
            float4 bv = *(const float4*)(&bias[col0]);
            float4 ov = {acc[mi][ni][0] + bv.x, acc[mi][ni][1] + bv.y,
                         acc[mi][ni][2] + bv.z, acc[mi][ni][3] + bv.w};
            *(float4*)(&out[(size_t)row * 1024 + col0]) = ov;
        }
    }
}

// ---------------- flash attention (R20: split MFMA chains) ----------------
__global__ __launch_bounds__(256, 2) void attn_kernel(
    const bf16* __restrict__ Q, const bf16* __restrict__ K,
    const bf16* __restrict__ VT, const bf16* __restrict__ maskb,
    bf16* __restrict__ vals) {
    __shared__ __attribute__((aligned(16))) char lds[4][8192];  // [buf]: K[0,4K) V[4K,8K)

    int blk = blockIdx.x;
    int bh = ((blk & 7) << 2) | ((blk >> 3) & 3);
    int qt = blk >> 5;                      // 0..15
    int t = threadIdx.x;
    int w = t >> 6, lane = t & 63;
    int l32 = lane & 31, hi = lane >> 5;
    int qw = qt * 128 + w * 32;             // wave's 32-q base

    const bf16* Qp = Q + (size_t)bh * 2048 * 64;
    const bf16* Kp = K + (size_t)bh * 2048 * 64;
    const bf16* Vp = VT + (size_t)bh * 64 * 2048;
    const bf16* mrowb = maskb + (size_t)(qw + l32) * 2048 + hi * 16;

    // staging (identical to R9/R15..R19)
    int ks_row = t >> 3;
    int ks_cblk = (t & 7) ^ (ks_row & 7);
    const bf16* kg = Kp + ks_row * 64 + ks_cblk * 8;
    int vs_d = t >> 2;
    int vs_sblk = (t & 3) ^ ((t >> 3) & 3);
    const bf16* vg = Vp + (size_t)vs_d * 2048 + vs_sblk * 8;

    const float SCL = 0.125f * 1.44269504089f;

    // Q B-frags: 4 d-tiles of 16 (lane: col q=l32, rows d = t4*16 + hi*8 + 0..7)
    bf16x8 qf[4];
#pragma unroll
    for (int t4 = 0; t4 < 4; t4++)
        qf[t4] = *(const bf16x8*)(&Qp[(size_t)(qw + l32) * 64 + t4 * 16 + hi * 8]);

    // stage iters 0,1
    load_lds16(kg + 0, lds[0] + t * 16);
    load_lds16(vg + 0, lds[0] + 4096 + t * 16);
    bf16x8 mb0 = *(const bf16x8*)(&mrowb[0]);
    bf16x8 mb1 = *(const bf16x8*)(&mrowb[8]);
    load_lds16(kg + 32 * 64, lds[1] + t * 16);
    load_lds16(vg + 32, lds[1] + 4096 + t * 16);
    asm volatile("s_waitcnt vmcnt(0)" ::: "memory");
    asm volatile("s_barrier" ::: "memory");

    // split PV accumulators: chains of 1 instead of 2
    f32x16 o0a = {}, o0b = {}, o1a = {}, o1b = {};
    const f32x16 kZero = {};
    float la = 0.f;

    // PV-delay pipeline state (P=0 makes first-iter PV a no-op)
    union { unsigned u[4]; bf16x8 v; } pp0, pp1;
    pp0.u[0] = 0; pp0.u[1] = 0; pp0.u[2] = 0; pp0.u[3] = 0;
    pp1.u[0] = 0; pp1.u[1] = 0; pp1.u[2] = 0; pp1.u[3] = 0;
    bf16x8 vfp0 = {}, vfp1 = {}, vfp2 = {}, vfp3 = {};

    // LDS offsets are lane-invariant across iters; only buffer base changes.
    int slot0 = (l32 * 8 + ((2 * 0 + hi) ^ (l32 & 7))) * 16;
    int slot1 = (l32 * 8 + ((2 * 1 + hi) ^ (l32 & 7))) * 16;
    int slot2 = (l32 * 8 + ((2 * 2 + hi) ^ (l32 & 7))) * 16;
    int slot3 = (l32 * 8 + ((2 * 3 + hi) ^ (l32 & 7))) * 16;
    int d0l = l32, d1l = 32 + l32;
    int sv00 = 4096 + (d0l * 4 + ((2 * 0 + hi) ^ ((d0l >> 1) & 3))) * 16;
    int sv01 = 4096 + (d0l * 4 + ((2 * 1 + hi) ^ ((d0l >> 1) & 3))) * 16;
    int sv10 = 4096 + (d1l * 4 + ((2 * 0 + hi) ^ ((d1l >> 1) & 3))) * 16;
    int sv11 = 4096 + (d1l * 4 + ((2 * 1 + hi) ^ ((d1l >> 1) & 3))) * 16;
    bool hib = hi != 0;

    for (int j = 0; j < 64; j++) {
        const char* bufp = lds[j & 3];
        int jm = j + 1 < 64 ? j + 1 : 63;
        bf16x8 nmb0 = *(const bf16x8*)(&mrowb[jm * 32]);
        bf16x8 nmb1 = *(const bf16x8*)(&mrowb[jm * 32 + 8]);
        int jp = j + 2 < 64 ? j + 2 : 63;
        char* dstp = lds[(j + 2) & 3];
        load_lds16(kg + (size_t)jp * 32 * 64, dstp + t * 16);
        load_lds16(vg + jp * 32, dstp + 4096 + t * 16);
        // segment = 4 vmem (2 mask + 2 DMA); drain all but segments j-1, j
        asm volatile("s_waitcnt vmcnt(8)" ::: "memory");
        asm volatile("s_barrier" ::: "memory");

        // K frag reads (issue first, latency covered by PV below)
        bf16x8 kf0 = *(const bf16x8*)(&bufp[slot0]);
        bf16x8 kf1 = *(const bf16x8*)(&bufp[slot1]);
        bf16x8 kf2 = *(const bf16x8*)(&bufp[slot2]);
        bf16x8 kf3 = *(const bf16x8*)(&bufp[slot3]);

        // PV for tile j-1 — 4 fully independent MFMAs (chain depth 1)
        o0a = MFMA32(vfp0, pp0.v, o0a);
        o0b = MFMA32(vfp1, pp1.v, o0b);
        o1a = MFMA32(vfp2, pp0.v, o1a);
        o1b = MFMA32(vfp3, pp1.v, o1b);

        // QK^T: two independent 2-deep chains, merged at exp input
        f32x16 s_a, s_b;
        s_a = MFMA32(kf0, qf[0], kZero);
        s_b = MFMA32(kf2, qf[2], kZero);
        s_a = MFMA32(kf1, qf[1], s_a);
        s_b = MFMA32(kf3, qf[3], s_b);

        // softmax: reg r -> k = (r&3) + 8*(r>>2) + 4*hi; maskb perm delivers
        // exactly these 16 values as mb0[0..7], mb1[0..7] (pre-scaled by L2E)
        float p[16];
        p[0]  = EXP2((s_a[0]  + s_b[0])  * SCL + (float)mb0[0]);
        p[1]  = EXP2((s_a[1]  + s_b[1])  * SCL + (float)mb0[1]);
        p[2]  = EXP2((s_a[2]  + s_b[2])  * SCL + (float)mb0[2]);
        p[3]  = EXP2((s_a[3]  + s_b[3])  * SCL + (float)mb0[3]);
        p[4]  = EXP2((s_a[4]  + s_b[4])  * SCL + (float)mb0[4]);
        p[5]  = EXP2((s_a[5]  + s_b[5])  * SCL + (float)mb0[5]);
        p[6]  = EXP2((s_a[6]  + s_b[6])  * SCL + (float)mb0[6]);
        p[7]  = EXP2((s_a[7]  + s_b[7])  * SCL + (float)mb0[7]);
        p[8]  = EXP2((s_a[8]  + s_b[8])  * SCL + (float)mb1[0]);
        p[9]  = EXP2((s_a[9]  + s_b[9])  * SCL + (float)mb1[1]);
        p[10] = EXP2((s_a[10] + s_b[10]) * SCL + (float)mb1[2]);
        p[11] = EXP2((s_a[11] + s_b[11]) * SCL + (float)mb1[3]);
        p[12] = EXP2((s_a[12] + s_b[12]) * SCL + (float)mb1[4]);
        p[13] = EXP2((s_a[13] + s_b[13]) * SCL + (float)mb1[5]);
        p[14] = EXP2((s_a[14] + s_b[14]) * SCL + (float)mb1[6]);
        p[15] = EXP2((s_a[15] + s_b[15]) * SCL + (float)mb1[7]);
        {
            float a0 = p[0] + p[1], a1 = p[2] + p[3], a2 = p[4] + p[5], a3 = p[6] + p[7];
            float a4 = p[8] + p[9], a5 = p[10] + p[11], a6 = p[12] + p[13], a7 = p[14] + p[15];
            float b0 = a0 + a1, b1 = a2 + a3, b2 = a4 + a5, b3 = a6 + a7;
            la += (b0 + b1) + (b2 + b3);
        }

        // pack 16 f32 -> 8 dwords: dw[i] = bf16 pair (p[2i], p[2i+1])
        unsigned dw0, dw1, dw2, dw3, dw4, dw5, dw6, dw7;
        {
            union { bf16x2 h; unsigned u; } u;
            u.h = bf16x2{(bf16)p[0],  (bf16)p[1]};  dw0 = u.u;
            u.h = bf16x2{(bf16)p[2],  (bf16)p[3]};  dw1 = u.u;
            u.h = bf16x2{(bf16)p[4],  (bf16)p[5]};  dw2 = u.u;
            u.h = bf16x2{(bf16)p[6],  (bf16)p[7]};  dw3 = u.u;
            u.h = bf16x2{(bf16)p[8],  (bf16)p[9]};  dw4 = u.u;
            u.h = bf16x2{(bf16)p[10], (bf16)p[11]}; dw5 = u.u;
            u.h = bf16x2{(bf16)p[12], (bf16)p[13]}; dw6 = u.u;
            u.h = bf16x2{(bf16)p[14], (bf16)p[15]}; dw7 = u.u;
        }
        // send-select repack: one shfl serves both directions per pair.
        unsigned r0 = (unsigned)__shfl_xor((int)(hib ? dw0 : dw2), 32, 64);
        unsigned r1 = (unsigned)__shfl_xor((int)(hib ? dw1 : dw3), 32, 64);
        unsigned r2 = (unsigned)__shfl_xor((int)(hib ? dw4 : dw6), 32, 64);
        unsigned r3 = (unsigned)__shfl_xor((int)(hib ? dw5 : dw7), 32, 64);
        pp0.u[0] = hib ? r0 : dw0;
        pp0.u[1] = hib ? r1 : dw1;
        pp0.u[2] = hib ? dw2 : r0;
        pp0.u[3] = hib ? dw3 : r1;
        pp1.u[0] = hib ? r2 : dw4;
        pp1.u[1] = hib ? r3 : dw5;
        pp1.u[2] = hib ? dw6 : r2;
        pp1.u[3] = hib ? dw7 : r3;

        // V frag reads for tile j (consumed by PV at iter j+1)
        vfp0 = *(const bf16x8*)(&bufp[sv00]);
        vfp1 = *(const bf16x8*)(&bufp[sv01]);
        vfp2 = *(const bf16x8*)(&bufp[sv10]);
        vfp3 = *(const bf16x8*)(&bufp[sv11]);

        mb0 = nmb0; mb1 = nmb1;
    }
    // final PV (tile 63)
    o0a = MFMA32(vfp0, pp0.v, o0a);
    o0b = MFMA32(vfp1, pp1.v, o0b);
    o1a = MFMA32(vfp2, pp0.v, o1a);
    o1b = MFMA32(vfp3, pp1.v, o1b);
    asm volatile("s_waitcnt vmcnt(0)" ::: "memory");

    // merge split accumulators (once)
    f32x16 o0 = o0a + o0b;
    f32x16 o1 = o1a + o1b;

    la += __shfl_xor(la, 32, 64);  // hi/lo halves cover complementary k-subsets
    int b = bh >> 4, hh = bh & 15;
    float li = 1.f / la;
    size_t row = (size_t)(b * 2048 + qw + l32);
    // O^T C-layout: reg r -> d = (r&3) + 8*(r>>2) + 4*hi (+32 for o1)
#pragma unroll
    for (int rg = 0; rg < 4; rg++) {
        bf16x4 pk0 = {(bf16)(o0[rg * 4 + 0] * li), (bf16)(o0[rg * 4 + 1] * li),
                      (bf16)(o0[rg * 4 + 2] * li), (bf16)(o0[rg * 4 + 3] * li)};
        *(bf16x4*)(&vals[row * 1024 + hh * 64 + rg * 8 + hi * 4]) = pk0;
        bf16x4 pk1 = {(bf16)(o1[rg * 4 + 0] * li), (bf16)(o1[rg * 4 + 1] * li),
                      (bf16)(o1[rg * 4 + 2] * li), (bf16)(o1[rg * 4 + 3] * li)};
        *(bf16x4*)(&vals[row * 1024 + hh * 64 + 32 + rg * 8 + hi * 4]) = pk1;
    }
}

// ---------------- launch ----------------
extern "C" void kernel_launch(void* const* d_in, const int* in_sizes, int n_in,
                              void* d_out, int out_size, void* d_ws, size_t ws_size,
                              hipStream_t stream) {
    const float* x     = (const float*)d_in[0];
    const float* mask  = (const float*)d_in[1];
    const float* w_qkv = (const float*)d_in[2];
    const float* b_qkv = (const float*)d_in[3];
    const float* w_out = (const float*)d_in[4];
    const float* b_out = (const float*)d_in[5];
    float* out = (float*)d_out;

    char* ws = (char*)d_ws;
    size_t off = 0;
    bf16* xb    = (bf16*)(ws + off); off += (size_t)4096 * 1024 * 2;
    bf16* wqkvT = (bf16*)(ws + off); off += (size_t)3072 * 1024 * 2;
    bf16* woutT = (bf16*)(ws + off); off += (size_t)1024 * 1024 * 2;
    bf16* Qa    = (bf16*)(ws + off); off += (size_t)32 * 2048 * 64 * 2;
    bf16* Ka    = (bf16*)(ws + off); off += (size_t)32 * 2048 * 64 * 2;
    bf16* VTa   = (bf16*)(ws + off); off += (size_t)32 * 64 * 2048 * 2;
    bf16* vals  = (bf16*)(ws + off); off += (size_t)4096 * 1024 * 2;
    bf16* maskb = (bf16*)(ws + off); off += (size_t)2048 * 2048 * 2;

    prep_kernel<<<8192, 256, 0, stream>>>(x, xb, w_qkv, wqkvT, w_out, woutT);
    gemm_qkv_kernel<<<4864, 256, 0, stream>>>(xb, wqkvT, b_qkv, Qa, Ka, VTa, mask, maskb);
    attn_kernel<<<512, 256, 0, stream>>>(Qa, Ka, VTa, maskb, vals);
    gemm_out_kernel<<<dim3(32, 16), 256, 0, stream>>>(vals, woutT, b_out, out);
}

// Round 12
// 207.623 us; speedup vs baseline: 1.0092x; 1.0092x over previous
//
#include <hip/hip_runtime.h>

// MHA: B=2, S=2048, D=1024, H=16, hd=64. fp32 in/out, bf16 MFMA internally.
// R21 == R19 (measured best: 208.7us total; attn 66.4us). R20's chain-split
// regressed (VALU-issue-bound: +16 v_add/iter -> +3.6% VALUBusy, +2.5us),
// confirming the attn floor is issue-bandwidth, not latency. Reverted.
// Final structure:
//  prep: cast x + transpose w_qkv/w_out (1 launch).
//  gemm_qkv + mask-prep fused launch (mask*log2e -> bf16, permuted).
//  attn: 32x32 MFMA swapped-operand QK^T (lane owns q-row), PV-delay
//    pipeline, send-select 4-shfl repack, bf16 permuted pre-scaled mask,
//    4 LDS bufs, dist-2 DMA prefetch, vmcnt(8).
//  gemm_out.

typedef __bf16 bf16;
typedef __bf16 bf16x2 __attribute__((ext_vector_type(2)));
typedef __bf16 bf16x4 __attribute__((ext_vector_type(4)));
typedef __bf16 bf16x8 __attribute__((ext_vector_type(8)));
typedef float f32x4 __attribute__((ext_vector_type(4)));
typedef float f32x16 __attribute__((ext_vector_type(16)));

#define MFMA(a, b, c) __builtin_amdgcn_mfma_f32_16x16x32_bf16((a), (b), (c), 0, 0, 0)
#define MFMA32(a, b, c) __builtin_amdgcn_mfma_f32_32x32x16_bf16((a), (b), (c), 0, 0, 0)

#if __has_builtin(__builtin_amdgcn_exp2f)
#define EXP2(x) __builtin_amdgcn_exp2f(x)
#else
#define EXP2(x) exp2f(x)
#endif

__device__ __forceinline__ void load_lds16(const bf16* g, void* l) {
    __builtin_amdgcn_global_load_lds(
        (const __attribute__((address_space(1))) unsigned int*)g,
        (__attribute__((address_space(3))) unsigned int*)l, 16, 0, 0);
}

// ---------------- prep: cast x, transpose w_qkv/w_out ----------------
__global__ __launch_bounds__(256) void prep_kernel(
    const float* __restrict__ x, bf16* __restrict__ xb,
    const float* __restrict__ w_qkv, bf16* __restrict__ wqkvT,
    const float* __restrict__ w_out, bf16* __restrict__ woutT) {
    __shared__ float tile[32][33];
    int blk = blockIdx.x;
    int t = threadIdx.x;
    if (blk < 4096) {
        int i = blk * 256 + t;
        float4 v = ((const float4*)x)[i];
        bf16x4 o = {(bf16)v.x, (bf16)v.y, (bf16)v.z, (bf16)v.w};
        ((bf16x4*)xb)[i] = o;
    } else if (blk < 4096 + 3072) {
        int flat = blk - 4096;
        int bx = (flat % 96) * 32, by = (flat / 96) * 32;
        int tx = t & 31, ty = t >> 5;
        for (int i = 0; i < 32; i += 8)
            tile[ty + i][tx] = w_qkv[(size_t)(by + ty + i) * 3072 + bx + tx];
        __syncthreads();
        for (int i = 0; i < 32; i += 8)
            wqkvT[(size_t)(bx + ty + i) * 1024 + by + tx] = (bf16)tile[tx][ty + i];
    } else {
        int flat = blk - (4096 + 3072);
        int bx = (flat % 32) * 32, by = (flat / 32) * 32;
        int tx = t & 31, ty = t >> 5;
        for (int i = 0; i < 32; i += 8)
            tile[ty + i][tx] = w_out[(size_t)(by + ty + i) * 1024 + bx + tx];
        __syncthreads();
        for (int i = 0; i < 32; i += 8)
            woutT[(size_t)(bx + ty + i) * 1024 + by + tx] = (bf16)tile[tx][ty + i];
    }
}

// ---------------- GEMM1 + mask prep (fused launch) ----------------
__global__ __launch_bounds__(256) void gemm_qkv_kernel(
    const bf16* __restrict__ A, const bf16* __restrict__ BT,
    const float* __restrict__ bias,
    bf16* __restrict__ Q, bf16* __restrict__ K, bf16* __restrict__ VT,
    const float* __restrict__ mask, bf16* __restrict__ maskb) {
    __shared__ __attribute__((aligned(16))) char lds[2][16384];  // A[0,8K) B[8K,16K)
    int blk0 = blockIdx.x;
    int t = threadIdx.x;
    if (blk0 >= 768) {
        // ---- mask prep branch (no barriers; uniform per block) ----
        int flat = blk0 - 768;
        int idx4 = flat * 256 + t;          // 0 .. 2048*2048/4-1
        float4 v = ((const float4*)mask)[idx4];
        int row = idx4 >> 9;                // 512 float4 per row
        int k = (idx4 & 511) * 4;
        int g = (k & 31) >> 2;
        int pos = (k & ~31) + ((g & 1) << 4) + ((g >> 1) << 2);
        const float L2E = 1.44269504089f;
        bf16x4 o = {(bf16)(v.x * L2E), (bf16)(v.y * L2E),
                    (bf16)(v.z * L2E), (bf16)(v.w * L2E)};
        *(bf16x4*)(&maskb[(size_t)row * 2048 + pos]) = o;
        return;
    }
    int bm = blk0 & 31, bn = blk0 >> 5;
    int w = t >> 6, lane = t & 63, g = lane >> 4, l16 = lane & 15;
    int wm = (w >> 1) * 64, wn = (w & 1) * 64;
    f32x4 acc[4][4] = {};
    const bf16* Ablk = A + (size_t)(bm * 128) * 1024;
    const bf16* Bblk = BT + (size_t)(bn * 128) * 1024;
    int srow = t >> 2;
    int scg = (t & 3) ^ (srow & 3);
    const bf16* ag0 = Ablk + (size_t)srow * 1024 + scg * 8;
    const bf16* ag1 = ag0 + 64 * 1024;
    const bf16* bg0 = Bblk + (size_t)srow * 1024 + scg * 8;
    const bf16* bg1 = bg0 + 64 * 1024;

    load_lds16(ag0, lds[0] + t * 16);
    load_lds16(ag1, lds[0] + 4096 + t * 16);
    load_lds16(bg0, lds[0] + 8192 + t * 16);
    load_lds16(bg1, lds[0] + 12288 + t * 16);
    asm volatile("s_waitcnt vmcnt(0)" ::: "memory");

    int sw = l16 & 3;
#pragma unroll 2
    for (int j = 0; j < 32; j++) {
        asm volatile("s_barrier" ::: "memory");
        int jp = j + 1 < 32 ? j + 1 : 31;
        char* dst = lds[(j + 1) & 1];
        load_lds16(ag0 + jp * 32, dst + t * 16);
        load_lds16(ag1 + jp * 32, dst + 4096 + t * 16);
        load_lds16(bg0 + jp * 32, dst + 8192 + t * 16);
        load_lds16(bg1 + jp * 32, dst + 12288 + t * 16);

        const bf16* As = (const bf16*)lds[j & 1];
        const bf16* Bs = (const bf16*)(lds[j & 1] + 8192);
        bf16x8 af[4], bfr[4];
#pragma unroll
        for (int mi = 0; mi < 4; mi++) {
            int row = wm + mi * 16 + l16;
            af[mi] = *(const bf16x8*)(&As[row * 32 + (g ^ sw) * 8]);
        }
#pragma unroll
        for (int ni = 0; ni < 4; ni++) {
            int row = wn + ni * 16 + l16;
            bfr[ni] = *(const bf16x8*)(&Bs[row * 32 + (g ^ sw) * 8]);
        }
#pragma unroll
        for (int mi = 0; mi < 4; mi++)
#pragma unroll
            for (int ni = 0; ni < 4; ni++)
                acc[mi][ni] = MFMA(bfr[ni], af[mi], acc[mi][ni]);  // D^T
        asm volatile("s_waitcnt vmcnt(0)" ::: "memory");
    }
    __syncthreads();  // publish all DMA before LDS reuse as vtile

    bf16* vt = (bf16*)lds;  // V-half transpose tile [64 d][136 s]
    int b = bm >> 4;
    int row0 = (bm & 15) * 128 + wm;
    int half_col = bn * 128 + wn;
    int h = half_col / 192, tt = half_col % 192;  // wave-uniform
    size_t bh = (size_t)(b * 16 + h);

    if (tt < 128) {
        bf16* base = (tt == 0 ? Q : K) + bh * 2048 * 64;
#pragma unroll
        for (int mi = 0; mi < 4; mi++) {
#pragma unroll
            for (int ni = 0; ni < 4; ni++) {
                int d0 = ni * 16 + g * 4;
                float4 bv = *(const float4*)(&bias[half_col + d0]);
                int s = row0 + mi * 16 + l16;
                bf16x4 pk = {(bf16)(acc[mi][ni][0] + bv.x), (bf16)(acc[mi][ni][1] + bv.y),
                             (bf16)(acc[mi][ni][2] + bv.z), (bf16)(acc[mi][ni][3] + bv.w)};
                *(bf16x4*)(&base[(size_t)s * 64 + d0]) = pk;
            }
        }
    } else {
#pragma unroll
        for (int mi = 0; mi < 4; mi++) {
            int s_local = wm + mi * 16 + l16;
#pragma unroll
            for (int ni = 0; ni < 4; ni++) {
                int d0 = ni * 16 + g * 4;
                float4 bv = *(const float4*)(&bias[half_col + d0]);
                vt[(d0 + 0) * 136 + s_local] = (bf16)(acc[mi][ni][0] + bv.x);
                vt[(d0 + 1) * 136 + s_local] = (bf16)(acc[mi][ni][1] + bv.y);
                vt[(d0 + 2) * 136 + s_local] = (bf16)(acc[mi][ni][2] + bv.z);
                vt[(d0 + 3) * 136 + s_local] = (bf16)(acc[mi][ni][3] + bv.w);
            }
        }
    }
    __syncthreads();

    int hc0 = bn * 128, hc1 = bn * 128 + 64;
    int vhalf = (hc0 % 192 == 128) ? 0 : ((hc1 % 192 == 128) ? 1 : -1);
    if (vhalf >= 0) {
        int vcol = bn * 128 + vhalf * 64;
        size_t vbh = (size_t)(b * 16 + vcol / 192);
        int d = t >> 2, ch = t & 3;
        const bf16* src = &vt[d * 136 + ch * 32];
        bf16* dstp = &VT[(vbh * 64 + d) * 2048 + (bm & 15) * 128 + ch * 32];
#pragma unroll
        for (int k = 0; k < 4; k++)
            *(bf16x8*)(&dstp[k * 8]) = *(const bf16x8*)(&src[k * 8]);
    }
}

// ---------------- GEMM3: vals[4096,1024] @ Wout -> out fp32 ----------------
__global__ __launch_bounds__(256) void gemm_out_kernel(
    const bf16* __restrict__ A, const bf16* __restrict__ BT,
    const float* __restrict__ bias, float* __restrict__ out) {
    __shared__ __attribute__((aligned(16))) char lds[2][12288];  // A[0,8K) B[8K,12K)
    int bm = blockIdx.x, bn = blockIdx.y;
    int t = threadIdx.x;
    int w = t >> 6, lane = t & 63, g = lane >> 4, l16 = lane & 15;
    int wm = (w >> 1) * 64, wn = (w & 1) * 32;
    f32x4 acc[4][2] = {};
    const bf16* Ablk = A + (size_t)(bm * 128) * 1024;
    const bf16* Bblk = BT + (size_t)(bn * 64) * 1024;
    int srow = t >> 2;
    int scg = (t & 3) ^ (srow & 3);
    const bf16* ag0 = Ablk + (size_t)srow * 1024 + scg * 8;
    const bf16* ag1 = ag0 + 64 * 1024;
    const bf16* bg0 = Bblk + (size_t)srow * 1024 + scg * 8;

    load_lds16(ag0, lds[0] + t * 16);
    load_lds16(ag1, lds[0] + 4096 + t * 16);
    load_lds16(bg0, lds[0] + 8192 + t * 16);
    asm volatile("s_waitcnt vmcnt(0)" ::: "memory");

    int sw = l16 & 3;
#pragma unroll 2
    for (int j = 0; j < 32; j++) {
        asm volatile("s_barrier" ::: "memory");
        int jp = j + 1 < 32 ? j + 1 : 31;
        char* dst = lds[(j + 1) & 1];
        load_lds16(ag0 + jp * 32, dst + t * 16);
        load_lds16(ag1 + jp * 32, dst + 4096 + t * 16);
        load_lds16(bg0 + jp * 32, dst + 8192 + t * 16);

        const bf16* As = (const bf16*)lds[j & 1];
        const bf16* Bs = (const bf16*)(lds[j & 1] + 8192);
        bf16x8 af[4], bfr[2];
#pragma unroll
        for (int mi = 0; mi < 4; mi++) {
            int row = wm + mi * 16 + l16;
            af[mi] = *(const bf16x8*)(&As[row * 32 + (g ^ sw) * 8]);
        }
#pragma unroll
        for (int ni = 0; ni < 2; ni++) {
            int row = wn + ni * 16 + l16;
            bfr[ni] = *(const bf16x8*)(&Bs[row * 32 + (g ^ sw) * 8]);
        }
#pragma unroll
        for (int mi = 0; mi < 4; mi++)
#pragma unroll
            for (int ni = 0; ni < 2; ni++)
                acc[mi][ni] = MFMA(bfr[ni], af[mi], acc[mi][ni]);  // D^T
        asm volatile("s_waitcnt vmcnt(0)" ::: "memory");
    }

#pragma unroll
    for (int mi = 0; mi < 4; mi++) {
#pragma unroll
        for (int ni = 0; ni < 2; ni++) {
            int row = bm * 128 + wm + mi * 16 + l16;
            int col0 = bn * 64 + wn + ni * 16 + g * 4;
            float4 bv = *(const float4*)(&bias[col0]);
            float4 ov = {acc[mi][ni][0] + bv.x, acc[mi][ni][1] + bv.y,
                         acc[mi][ni][2] + bv.z, acc[mi][ni][3] + bv.w};
            *(float4*)(&out[(size_t)row * 1024 + col0]) = ov;
        }
    }
}

// ---------------- flash attention (final: R17/R19 core) ----------------
__global__ __launch_bounds__(256, 2) void attn_kernel(
    const bf16* __restrict__ Q, const bf16* __restrict__ K,
    const bf16* __restrict__ VT, const bf16* __restrict__ maskb,
    bf16* __restrict__ vals) {
    __shared__ __attribute__((aligned(16))) char lds[4][8192];  // [buf]: K[0,4K) V[4K,8K)

    int blk = blockIdx.x;
    int bh = ((blk & 7) << 2) | ((blk >> 3) & 3);
    int qt = blk >> 5;                      // 0..15
    int t = threadIdx.x;
    int w = t >> 6, lane = t & 63;
    int l32 = lane & 31, hi = lane >> 5;
    int qw = qt * 128 + w * 32;             // wave's 32-q base

    const bf16* Qp = Q + (size_t)bh * 2048 * 64;
    const bf16* Kp = K + (size_t)bh * 2048 * 64;
    const bf16* Vp = VT + (size_t)bh * 64 * 2048;
    const bf16* mrowb = maskb + (size_t)(qw + l32) * 2048 + hi * 16;

    // staging
    int ks_row = t >> 3;
    int ks_cblk = (t & 7) ^ (ks_row & 7);
    const bf16* kg = Kp + ks_row * 64 + ks_cblk * 8;
    int vs_d = t >> 2;
    int vs_sblk = (t & 3) ^ ((t >> 3) & 3);
    const bf16* vg = Vp + (size_t)vs_d * 2048 + vs_sblk * 8;

    const float SCL = 0.125f * 1.44269504089f;

    // Q B-frags: 4 d-tiles of 16 (lane: col q=l32, rows d = t4*16 + hi*8 + 0..7)
    bf16x8 qf[4];
#pragma unroll
    for (int t4 = 0; t4 < 4; t4++)
        qf[t4] = *(const bf16x8*)(&Qp[(size_t)(qw + l32) * 64 + t4 * 16 + hi * 8]);

    // stage iters 0,1
    load_lds16(kg + 0, lds[0] + t * 16);
    load_lds16(vg + 0, lds[0] + 4096 + t * 16);
    bf16x8 mb0 = *(const bf16x8*)(&mrowb[0]);
    bf16x8 mb1 = *(const bf16x8*)(&mrowb[8]);
    load_lds16(kg + 32 * 64, lds[1] + t * 16);
    load_lds16(vg + 32, lds[1] + 4096 + t * 16);
    asm volatile("s_waitcnt vmcnt(0)" ::: "memory");
    asm volatile("s_barrier" ::: "memory");

    f32x16 o0 = {}, o1 = {};
    const f32x16 kZero = {};
    float la = 0.f;

    // PV-delay pipeline state (P=0 makes first-iter PV a no-op)
    union { unsigned u[4]; bf16x8 v; } pp0, pp1;
    pp0.u[0] = 0; pp0.u[1] = 0; pp0.u[2] = 0; pp0.u[3] = 0;
    pp1.u[0] = 0; pp1.u[1] = 0; pp1.u[2] = 0; pp1.u[3] = 0;
    bf16x8 vfp0 = {}, vfp1 = {}, vfp2 = {}, vfp3 = {};

    // LDS offsets are lane-invariant across iters; only buffer base changes.
    int slot0 = (l32 * 8 + ((2 * 0 + hi) ^ (l32 & 7))) * 16;
    int slot1 = (l32 * 8 + ((2 * 1 + hi) ^ (l32 & 7))) * 16;
    int slot2 = (l32 * 8 + ((2 * 2 + hi) ^ (l32 & 7))) * 16;
    int slot3 = (l32 * 8 + ((2 * 3 + hi) ^ (l32 & 7))) * 16;
    int d0l = l32, d1l = 32 + l32;
    int sv00 = 4096 + (d0l * 4 + ((2 * 0 + hi) ^ ((d0l >> 1) & 3))) * 16;
    int sv01 = 4096 + (d0l * 4 + ((2 * 1 + hi) ^ ((d0l >> 1) & 3))) * 16;
    int sv10 = 4096 + (d1l * 4 + ((2 * 0 + hi) ^ ((d1l >> 1) & 3))) * 16;
    int sv11 = 4096 + (d1l * 4 + ((2 * 1 + hi) ^ ((d1l >> 1) & 3))) * 16;
    bool hib = hi != 0;

    for (int j = 0; j < 64; j++) {
        const char* bufp = lds[j & 3];
        int jm = j + 1 < 64 ? j + 1 : 63;
        bf16x8 nmb0 = *(const bf16x8*)(&mrowb[jm * 32]);
        bf16x8 nmb1 = *(const bf16x8*)(&mrowb[jm * 32 + 8]);
        int jp = j + 2 < 64 ? j + 2 : 63;
        char* dstp = lds[(j + 2) & 3];
        load_lds16(kg + (size_t)jp * 32 * 64, dstp + t * 16);
        load_lds16(vg + jp * 32, dstp + 4096 + t * 16);
        // segment = 4 vmem (2 mask + 2 DMA); drain all but segments j-1, j
        asm volatile("s_waitcnt vmcnt(8)" ::: "memory");
        asm volatile("s_barrier" ::: "memory");

        // K frag reads (issue first, latency covered by PV below)
        bf16x8 kf0 = *(const bf16x8*)(&bufp[slot0]);
        bf16x8 kf1 = *(const bf16x8*)(&bufp[slot1]);
        bf16x8 kf2 = *(const bf16x8*)(&bufp[slot2]);
        bf16x8 kf3 = *(const bf16x8*)(&bufp[slot3]);

        // PV for tile j-1 (register-only; fills K-read + QK startup latency)
        o0 = MFMA32(vfp0, pp0.v, o0);
        o0 = MFMA32(vfp1, pp1.v, o0);
        o1 = MFMA32(vfp2, pp0.v, o1);
        o1 = MFMA32(vfp3, pp1.v, o1);

        // QK^T: 4 chained MFMAs over d-tiles
        f32x16 s;
        s = MFMA32(kf0, qf[0], kZero);
        s = MFMA32(kf1, qf[1], s);
        s = MFMA32(kf2, qf[2], s);
        s = MFMA32(kf3, qf[3], s);

        // softmax: reg r -> k = (r&3) + 8*(r>>2) + 4*hi; maskb perm delivers
        // exactly these 16 values as mb0[0..7], mb1[0..7] (pre-scaled by L2E)
        float p[16];
        p[0]  = EXP2(s[0]  * SCL + (float)mb0[0]);
        p[1]  = EXP2(s[1]  * SCL + (float)mb0[1]);
        p[2]  = EXP2(s[2]  * SCL + (float)mb0[2]);
        p[3]  = EXP2(s[3]  * SCL + (float)mb0[3]);
        p[4]  = EXP2(s[4]  * SCL + (float)mb0[4]);
        p[5]  = EXP2(s[5]  * SCL + (float)mb0[5]);
        p[6]  = EXP2(s[6]  * SCL + (float)mb0[6]);
        p[7]  = EXP2(s[7]  * SCL + (float)mb0[7]);
        p[8]  = EXP2(s[8]  * SCL + (float)mb1[0]);
        p[9]  = EXP2(s[9]  * SCL + (float)mb1[1]);
        p[10] = EXP2(s[10] * SCL + (float)mb1[2]);
        p[11] = EXP2(s[11] * SCL + (float)mb1[3]);
        p[12] = EXP2(s[12] * SCL + (float)mb1[4]);
        p[13] = EXP2(s[13] * SCL + (float)mb1[5]);
        p[14] = EXP2(s[14] * SCL + (float)mb1[6]);
        p[15] = EXP2(s[15] * SCL + (float)mb1[7]);
        {
            float a0 = p[0] + p[1], a1 = p[2] + p[3], a2 = p[4] + p[5], a3 = p[6] + p[7];
            float a4 = p[8] + p[9], a5 = p[10] + p[11], a6 = p[12] + p[13], a7 = p[14] + p[15];
            float b0 = a0 + a1, b1 = a2 + a3, b2 = a4 + a5, b3 = a6 + a7;
            la += (b0 + b1) + (b2 + b3);
        }

        // pack 16 f32 -> 8 dwords: dw[i] = bf16 pair (p[2i], p[2i+1])
        unsigned dw0, dw1, dw2, dw3, dw4, dw5, dw6, dw7;
        {
            union { bf16x2 h; unsigned u; } u;
            u.h = bf16x2{(bf16)p[0],  (bf16)p[1]};  dw0 = u.u;
            u.h = bf16x2{(bf16)p[2],  (bf16)p[3]};  dw1 = u.u;
            u.h = bf16x2{(bf16)p[4],  (bf16)p[5]};  dw2 = u.u;
            u.h = bf16x2{(bf16)p[6],  (bf16)p[7]};  dw3 = u.u;
            u.h = bf16x2{(bf16)p[8],  (bf16)p[9]};  dw4 = u.u;
            u.h = bf16x2{(bf16)p[10], (bf16)p[11]}; dw5 = u.u;
            u.h = bf16x2{(bf16)p[12], (bf16)p[13]}; dw6 = u.u;
            u.h = bf16x2{(bf16)p[14], (bf16)p[15]}; dw7 = u.u;
        }
        // send-select repack: one shfl serves both directions per pair.
        unsigned r0 = (unsigned)__shfl_xor((int)(hib ? dw0 : dw2), 32, 64);
        unsigned r1 = (unsigned)__shfl_xor((int)(hib ? dw1 : dw3), 32, 64);
        unsigned r2 = (unsigned)__shfl_xor((int)(hib ? dw4 : dw6), 32, 64);
        unsigned r3 = (unsigned)__shfl_xor((int)(hib ? dw5 : dw7), 32, 64);
        pp0.u[0] = hib ? r0 : dw0;
        pp0.u[1] = hib ? r1 : dw1;
        pp0.u[2] = hib ? dw2 : r0;
        pp0.u[3] = hib ? dw3 : r1;
        pp1.u[0] = hib ? r2 : dw4;
        pp1.u[1] = hib ? r3 : dw5;
        pp1.u[2] = hib ? dw6 : r2;
        pp1.u[3] = hib ? dw7 : r3;

        // V frag reads for tile j (consumed by PV at iter j+1)
        vfp0 = *(const bf16x8*)(&bufp[sv00]);
        vfp1 = *(const bf16x8*)(&bufp[sv01]);
        vfp2 = *(const bf16x8*)(&bufp[sv10]);
        vfp3 = *(const bf16x8*)(&bufp[sv11]);

        mb0 = nmb0; mb1 = nmb1;
    }
    // final PV (tile 63)
    o0 = MFMA32(vfp0, pp0.v, o0);
    o0 = MFMA32(vfp1, pp1.v, o0);
    o1 = MFMA32(vfp2, pp0.v, o1);
    o1 = MFMA32(vfp3, pp1.v, o1);
    asm volatile("s_waitcnt vmcnt(0)" ::: "memory");

    la += __shfl_xor(la, 32, 64);  // hi/lo halves cover complementary k-subsets
    int b = bh >> 4, hh = bh & 15;
    float li = 1.f / la;
    size_t row = (size_t)(b * 2048 + qw + l32);
    // O^T C-layout: reg r -> d = (r&3) + 8*(r>>2) + 4*hi (+32 for o1)
#pragma unroll
    for (int rg = 0; rg < 4; rg++) {
        bf16x4 pk0 = {(bf16)(o0[rg * 4 + 0] * li), (bf16)(o0[rg * 4 + 1] * li),
                      (bf16)(o0[rg * 4 + 2] * li), (bf16)(o0[rg * 4 + 3] * li)};
        *(bf16x4*)(&vals[row * 1024 + hh * 64 + rg * 8 + hi * 4]) = pk0;
        bf16x4 pk1 = {(bf16)(o1[rg * 4 + 0] * li), (bf16)(o1[rg * 4 + 1] * li),
                      (bf16)(o1[rg * 4 + 2] * li), (bf16)(o1[rg * 4 + 3] * li)};
        *(bf16x4*)(&vals[row * 1024 + hh * 64 + 32 + rg * 8 + hi * 4]) = pk1;
    }
}

// ---------------- launch ----------------
extern "C" void kernel_launch(void* const* d_in, const int* in_sizes, int n_in,
                              void* d_out, int out_size, void* d_ws, size_t ws_size,
                              hipStream_t stream) {
    const float* x     = (const float*)d_in[0];
    const float* mask  = (const float*)d_in[1];
    const float* w_qkv = (const float*)d_in[2];
    const float* b_qkv = (const float*)d_in[3];
    const float* w_out = (const float*)d_in[4];
    const float* b_out = (const float*)d_in[5];
    float* out = (float*)d_out;

    char* ws = (char*)d_ws;
    size_t off = 0;
    bf16* xb    = (bf16*)(ws + off); off += (size_t)4096 * 1024 * 2;
    bf16* wqkvT = (bf16*)(ws + off); off += (size_t)3072 * 1024 * 2;
    bf16* woutT = (bf16*)(ws + off); off += (size_t)1024 * 1024 * 2;
    bf16* Qa    = (bf16*)(ws + off); off += (size_t)32 * 2048 * 64 * 2;
    bf16* Ka    = (bf16*)(ws + off); off += (size_t)32 * 2048 * 64 * 2;
    bf16* VTa   = (bf16*)(ws + off); off += (size_t)32 * 64 * 2048 * 2;
    bf16* vals  = (bf16*)(ws + off); off += (size_t)4096 * 1024 * 2;
    bf16* maskb = (bf16*)(ws + off); off += (size_t)2048 * 2048 * 2;

    prep_kernel<<<8192, 256, 0, stream>>>(x, xb, w_qkv, wqkvT, w_out, woutT);
    gemm_qkv_kernel<<<4864, 256, 0, stream>>>(xb, wqkvT, b_qkv, Qa, Ka, VTa, mask, maskb);
    attn_kernel<<<512, 256, 0, stream>>>(Qa, Ka, VTa, maskb, vals);
    gemm_out_kernel<<<dim3(32, 16), 256, 0, stream>>>(vals, woutT, b_out, out);
}